// Round 18
// baseline (207.925 us; speedup 1.0000x reference)
//
#include <hip/hip_runtime.h>
#include <math.h>

#define B_ 8
#define L_ 4096
#define DM 128
#define DI 256
#define DSN 16
#define RK 8
#define M_ (B_*L_)      // 32768 positions
#define NC 128          // number of scan chunks
#define CH 32           // chunk length (NC*CH == L_)

typedef __attribute__((ext_vector_type(8))) short bfrag;   // 8 bf16 (4 VGPRs)
typedef __attribute__((ext_vector_type(4))) float ffrag;   // 4 fp32 acc
typedef __attribute__((ext_vector_type(2))) float f32x2;   // packed-math pair

// fast silu: v_exp + v_rcp (hardware approx, ~22-bit — far above bf16 needs)
__device__ __forceinline__ float silu_f(float x) {
  return x * __builtin_amdgcn_rcpf(1.f + __expf(-x));
}
// fast softplus: v_exp + v_log instead of libm log1pf
__device__ __forceinline__ float softplus_f(float x) {
  return (x > 20.f) ? x : __logf(1.f + __expf(x));
}

__device__ __forceinline__ unsigned short f2bf(float f) {
  unsigned int u = __builtin_bit_cast(unsigned int, f);
  unsigned int r = (u + 0x7FFFu + ((u >> 16) & 1u)) >> 16;   // RNE
  return (unsigned short)r;
}
__device__ __forceinline__ unsigned int f2bf2(float lo, float hi) {
  return (unsigned int)f2bf(lo) | ((unsigned int)f2bf(hi) << 16);
}
__device__ __forceinline__ float bf2f(unsigned int us) {
  return __builtin_bit_cast(float, us << 16);
}

// ---------------------------------------------------------------------------
// in_proj bf16 MFMA GEMM, half-split + reg-prefetch W pipeline + LDS-staged
// vectorized output. Grid (2, 512): blockIdx.x = output half (0: xb, 1: zsb
// with fused silu).
// ---------------------------------------------------------------------------
__global__ __launch_bounds__(256)
void gemm_bf16_in(const float* __restrict__ A, const float* __restrict__ W,
                  unsigned short* __restrict__ xb, unsigned short* __restrict__ zsb) {
  __shared__ unsigned short As[64 * 136];   // 17.4 KB
  __shared__ unsigned short Ws[64 * 136];   // 17.4 KB
  __shared__ unsigned short Os[64 * 72];    // 9.2 KB (stride 72 -> 2-way, free)
  const int t = threadIdx.x;
  const int m0 = blockIdx.y << 6;
  const int half = blockIdx.x;              // 0 -> xb, 1 -> zsb (silu)
  unsigned short* __restrict__ outp = half ? zsb : xb;
  const float* __restrict__ Wbase = W + (half << 8) * 128;
  for (int i = t; i < 64 * 32; i += 256) {
    int row = i >> 5, c4 = i & 31;
    float4 av = *(const float4*)&A[(m0 + row) * 128 + (c4 << 2)];
    uint2 ap = {f2bf2(av.x, av.y), f2bf2(av.z, av.w)};
    *(uint2*)&As[row * 136 + (c4 << 2)] = ap;
  }
  float4 wr[8];
#pragma unroll
  for (int k = 0; k < 8; ++k) {
    int i = t + (k << 8);
    int row = i >> 5, c4 = i & 31;
    wr[k] = *(const float4*)&Wbase[row * 128 + (c4 << 2)];
  }
#pragma unroll
  for (int k = 0; k < 8; ++k) {
    int i = t + (k << 8);
    int row = i >> 5, c4 = i & 31;
    uint2 wp = {f2bf2(wr[k].x, wr[k].y), f2bf2(wr[k].z, wr[k].w)};
    *(uint2*)&Ws[row * 136 + (c4 << 2)] = wp;
  }
  __syncthreads();
  const int w = t >> 6, l = t & 63, q = l >> 4, col = l & 15;
  for (int jt = 0; jt < 4; ++jt) {
    if (jt < 3) {
#pragma unroll
      for (int k = 0; k < 8; ++k) {
        int i = t + (k << 8);
        int row = i >> 5, c4 = i & 31;
        wr[k] = *(const float4*)&Wbase[(((jt + 1) << 6) + row) * 128 + (c4 << 2)];
      }
    }
    ffrag acc[4] = {{0.f,0.f,0.f,0.f},{0.f,0.f,0.f,0.f},{0.f,0.f,0.f,0.f},{0.f,0.f,0.f,0.f}};
#pragma unroll
    for (int s = 0; s < 4; ++s) {
      int k0 = s * 32 + q * 8;
      bfrag af = *(const bfrag*)&As[((w << 4) + col) * 136 + k0];
#pragma unroll
      for (int nt = 0; nt < 4; ++nt) {
        bfrag bf_ = *(const bfrag*)&Ws[((nt << 4) + col) * 136 + k0];
        acc[nt] = __builtin_amdgcn_mfma_f32_16x16x32_bf16(af, bf_, acc[nt], 0, 0, 0);
      }
    }
    __syncthreads();
#pragma unroll
    for (int nt = 0; nt < 4; ++nt)
#pragma unroll
      for (int i = 0; i < 4; ++i) {
        int ml = (w << 4) + (q << 2) + i;
        float v = acc[nt][i];
        if (half) v = silu_f(v);
        Os[ml * 72 + (nt << 4) + col] = f2bf(v);
      }
    if (jt < 3) {
#pragma unroll
      for (int k = 0; k < 8; ++k) {
        int i = t + (k << 8);
        int row = i >> 5, c4 = i & 31;
        uint2 wp = {f2bf2(wr[k].x, wr[k].y), f2bf2(wr[k].z, wr[k].w)};
        *(uint2*)&Ws[row * 136 + (c4 << 2)] = wp;
      }
    }
    __syncthreads();
    {
      int r = t >> 2, c8 = (t & 3) << 3;
      int m = m0 + r;
      *(uint4*)&outp[m * 256 + (jt << 6) + c8]      = *(const uint4*)&Os[r * 72 + c8];
      *(uint4*)&outp[m * 256 + (jt << 6) + 32 + c8] = *(const uint4*)&Os[r * 72 + 32 + c8];
    }
  }
}

// ---------------------------------------------------------------------------
// out_proj bf16 MFMA GEMM: A = yb (bf16 gated, M x 256), W f32, K=256.
// ---------------------------------------------------------------------------
__global__ __launch_bounds__(256)
void gemm_bf16_out(const unsigned short* __restrict__ Ab, const float* __restrict__ W,
                   unsigned short* __restrict__ C) {
  __shared__ unsigned short As[64 * 264];
  __shared__ unsigned short Ws[64 * 264];
  const int t = threadIdx.x;
  const int m0 = blockIdx.y << 6, n0 = blockIdx.x << 6;
  for (int i = t; i < 64 * 32; i += 256) {
    int row = i >> 5, c8 = i & 31;
    uint4 av = *(const uint4*)&Ab[(m0 + row) * 256 + (c8 << 3)];
    *(uint4*)&As[row * 264 + (c8 << 3)] = av;
  }
  for (int i = t; i < 64 * 64; i += 256) {
    int row = i >> 6, c4 = i & 63;
    float4 wv = *(const float4*)&W[(n0 + row) * 256 + (c4 << 2)];
    uint2 wp = {f2bf2(wv.x, wv.y), f2bf2(wv.z, wv.w)};
    *(uint2*)&Ws[row * 264 + (c4 << 2)] = wp;
  }
  __syncthreads();
  const int w = t >> 6, l = t & 63, q = l >> 4, col = l & 15;
  ffrag acc[4] = {{0.f,0.f,0.f,0.f},{0.f,0.f,0.f,0.f},{0.f,0.f,0.f,0.f},{0.f,0.f,0.f,0.f}};
#pragma unroll
  for (int s = 0; s < 8; ++s) {
    int k0 = s * 32 + q * 8;
    bfrag af = *(const bfrag*)&As[((w << 4) + col) * 264 + k0];
#pragma unroll
    for (int nt = 0; nt < 4; ++nt) {
      bfrag bf_ = *(const bfrag*)&Ws[((nt << 4) + col) * 264 + k0];
      acc[nt] = __builtin_amdgcn_mfma_f32_16x16x32_bf16(af, bf_, acc[nt], 0, 0, 0);
    }
  }
#pragma unroll
  for (int nt = 0; nt < 4; ++nt)
#pragma unroll
    for (int i = 0; i < 4; ++i) {
      int ml = (w << 4) + (q << 2) + i;
      C[(m0 + ml) * 128 + n0 + (nt << 4) + col] = f2bf(acc[nt][i]);
    }
}

// ---------------------------------------------------------------------------
// Fused conv(4)+SiLU -> bf16 LDS -> MFMA x_proj -> dt_proj + softplus.
// ---------------------------------------------------------------------------
__global__ __launch_bounds__(512)
void xproj_dtproj(const unsigned short* __restrict__ xb, const float* __restrict__ xw,
                  const float* __restrict__ dtw, const float* __restrict__ dtpb,
                  const float* __restrict__ cw, const float* __restrict__ cb,
                  float* __restrict__ Bb, float* __restrict__ Cb,
                  unsigned int* __restrict__ udt) {
  __shared__ unsigned short ua[64 * 264];   // u bf16
  __shared__ unsigned short wb[48 * 264];   // xw bf16; rows 40..47 zeroed
  __shared__ float dtr_s[64 * 12];
  const int t = threadIdx.x;
  const int p0 = blockIdx.x << 6;
  {
    const int k = t & 255, half = t >> 8;
    const int pstart = half << 5;
    const int base = p0 + pstart;
    const int lb = base & (L_ - 1);
    const float w0 = cw[k*4], w1 = cw[k*4+1], w2 = cw[k*4+2], w3 = cw[k*4+3];
    const float bias = cb[k];
    float x0 = (lb >= 3) ? bf2f((unsigned int)xb[(base - 3) * 256 + k]) : 0.f;
    float x1 = (lb >= 2) ? bf2f((unsigned int)xb[(base - 2) * 256 + k]) : 0.f;
    float x2 = (lb >= 1) ? bf2f((unsigned int)xb[(base - 1) * 256 + k]) : 0.f;
#pragma unroll 8
    for (int it = 0; it < 32; ++it) {
      float x3 = bf2f((unsigned int)xb[(base + it) * 256 + k]);
      float u = silu_f(fmaf(w0, x0, fmaf(w1, x1, fmaf(w2, x2, fmaf(w3, x3, bias)))));
      ua[(pstart + it) * 264 + k] = f2bf(u);
      x0 = x1; x1 = x2; x2 = x3;
    }
  }
  for (int i = t; i < 40 * 256; i += 512) {
    int n = i >> 8, k = i & 255;
    wb[n * 264 + k] = f2bf(xw[i]);
  }
  for (int i = t; i < 8 * 264; i += 512) wb[40 * 264 + i] = 0;
  __syncthreads();
  const int w = t >> 6, l = t & 63, q = l >> 4, col = l & 15;
  for (int tile = w; tile < 12; tile += 8) {
    const int mt = tile & 3, nt = tile >> 2;
    ffrag acc = {0.f, 0.f, 0.f, 0.f};
#pragma unroll
    for (int s = 0; s < 8; ++s) {
      int k0 = s * 32 + q * 8;
      bfrag af = *(const bfrag*)&ua[((mt << 4) + col) * 264 + k0];
      bfrag bf_ = *(const bfrag*)&wb[((nt << 4) + col) * 264 + k0];
      acc = __builtin_amdgcn_mfma_f32_16x16x32_bf16(af, bf_, acc, 0, 0, 0);
    }
#pragma unroll
    for (int i = 0; i < 4; ++i) {
      int ml = (mt << 4) + (q << 2) + i;
      int m = p0 + ml;
      if (nt == 0) {
        if (col < 8) dtr_s[ml * 12 + col] = acc[i];
        else         Bb[m * 16 + (col - 8)] = acc[i];
      } else if (nt == 1) {
        if (col < 8) Bb[m * 16 + 8 + col] = acc[i];
        else         Cb[m * 16 + (col - 8)] = acc[i];
      } else {
        if (col < 8) Cb[m * 16 + 8 + col] = acc[i];
      }
    }
  }
  __syncthreads();
  {
    const int d = t & 255, half = t >> 8;
    const int pstart = half << 5;
    float w8[8];
    *(float4*)&w8[0] = *(const float4*)&dtw[d * 8];
    *(float4*)&w8[4] = *(const float4*)&dtw[d * 8 + 4];
    const float bias = dtpb[d];
#pragma unroll 4
    for (int pp = pstart; pp < pstart + 32; ++pp) {
      float r0[8];
      *(float4*)&r0[0] = *(const float4*)&dtr_s[pp * 12];
      *(float4*)&r0[4] = *(const float4*)&dtr_s[pp * 12 + 4];
      float a2 = bias;
#pragma unroll
      for (int r2 = 0; r2 < 8; ++r2) a2 = fmaf(r0[r2], w8[r2], a2);
      float sp = softplus_f(a2);
      udt[(p0 + pp) * 256 + d] =
          (unsigned int)ua[pp * 264 + d] | ((unsigned int)f2bf(sp) << 16);
    }
  }
}

// ---------------------------------------------------------------------------
// Scan phase 1 (CH=32, full occupancy): B staged to LDS; udt prefetch depth 2.
// cP/cHe stored bf16.
// ---------------------------------------------------------------------------
__global__ __launch_bounds__(512, 4)
void scan_phase1(const unsigned int* __restrict__ udt,
                 const float* __restrict__ Bb, const float* __restrict__ alog,
                 unsigned short* __restrict__ cP, unsigned short* __restrict__ cHe) {
  __shared__ float Bs[CH * 16];   // 2 KB
  const int bc = blockIdx.x;
  const int b = bc >> 7, c = bc & (NC - 1);
  const int t = threadIdx.x;
  const int l = t & 63, w = t >> 6;
  const int d = (w << 5) + (l & 31);
  const int sh = l >> 5;
  const int soff = sh << 3;
  const int base = b * L_ + c * CH;
  if (t < CH * 4) ((float4*)Bs)[t] = *(const float4*)&Bb[base * 16 + (t << 2)];
  float a[8];
  bool okl = true;
#pragma unroll
  for (int j = 0; j < 8; ++j) {
    a[j] = -__expf(alog[d * 16 + soff + j]);
    float tgt = (float)(soff + j + 1);
    okl = okl && (fabsf(a[j] + tgt) <= 1e-3f * tgt);
  }
  const bool fast = (bool)__all((int)okl);
  f32x2 h2[4] = {{0.f,0.f},{0.f,0.f},{0.f,0.f},{0.f,0.f}};
  float sdt = 0.f;
  unsigned int wv0 = udt[base * 256 + d];
  unsigned int wv1 = udt[(base + 1) * 256 + d];
  __syncthreads();
#pragma unroll 4
  for (int ll = 0; ll < CH; ++ll) {
    const int m2 = base + ((ll + 2 < CH) ? ll + 2 : CH - 1);
    unsigned int wv2 = udt[m2 * 256 + d];
    float4 b0 = *(const float4*)&Bs[ll * 16 + soff];
    float4 b1 = *(const float4*)&Bs[ll * 16 + soff + 4];
    float uv  = bf2f(wv0 & 0xFFFFu);
    float dtv = bf2f(wv0 >> 16);
    f32x2 B2[4] = {{b0.x,b0.y},{b0.z,b0.w},{b1.x,b1.y},{b1.z,b1.w}};
    float du = dtv * uv;
    sdt += dtv;
    if (fast) {
      float e1 = __expf(-dtv);
      float e2 = e1 * e1, e4 = e2 * e2, e8 = e4 * e4;
      float st = sh ? e8 * e1 : e1;
      f32x2 dA = {st, st * e1};
      f32x2 e22 = {e2, e2};
      f32x2 du2 = {du, du};
#pragma unroll
      for (int j = 0; j < 4; ++j) {
        h2[j] = dA * h2[j] + du2 * B2[j];
        dA = dA * e22;
      }
    } else {
#pragma unroll
      for (int j = 0; j < 8; ++j) {
        float dA = __expf(dtv * a[j]);
        h2[j >> 1][j & 1] = fmaf(dA, h2[j >> 1][j & 1], du * B2[j >> 1][j & 1]);
      }
    }
    wv0 = wv1; wv1 = wv2;
  }
#pragma unroll
  for (int j = 0; j < 8; ++j) {
    int o = (bc * 16 + soff + j) * 256 + d;
    cP[o]  = f2bf(__expf(a[j] * sdt));
    cHe[o] = f2bf(h2[j >> 1][j & 1]);
  }
}

// ---------------------------------------------------------------------------
// Hierarchical combine (NC=128, bf16): block = (b, 64-sd group); 512 thr =
// 64 sd x 8 segments of 16 chunks. Serial depth 16+8+16. h_start -> cP.
// ---------------------------------------------------------------------------
__global__ __launch_bounds__(512)
void scan_combine(unsigned short* __restrict__ cP, const unsigned short* __restrict__ cHe) {
  __shared__ float segP[64 * 9], segH[64 * 9], segS[64 * 9];
  const int t = threadIdx.x;
  const int sdl = t & 63, seg = t >> 6;
  const int blk = blockIdx.x;
  const int b = blk >> 6, grp = blk & 63;
  const int sd = (grp << 6) + sdl;
  const int base = b * NC * 4096 + sd;
  float Pacc = 1.f, Hacc = 0.f;
#pragma unroll
  for (int i = 0; i < 16; ++i) {
    int idx = base + (seg * 16 + i) * 4096;
    float p = bf2f((unsigned int)cP[idx]);
    float he = bf2f((unsigned int)cHe[idx]);
    Hacc = fmaf(p, Hacc, he);
    Pacc *= p;
  }
  segP[sdl * 9 + seg] = Pacc;
  segH[sdl * 9 + seg] = Hacc;
  __syncthreads();
  if (t < 64) {
    float hs = 0.f;
#pragma unroll
    for (int s2 = 0; s2 < 8; ++s2) {
      segS[t * 9 + s2] = hs;
      hs = fmaf(segP[t * 9 + s2], hs, segH[t * 9 + s2]);
    }
  }
  __syncthreads();
  float hs = segS[sdl * 9 + seg];
#pragma unroll
  for (int i = 0; i < 16; ++i) {
    int idx = base + (seg * 16 + i) * 4096;
    float p = bf2f((unsigned int)cP[idx]);
    float he = bf2f((unsigned int)cHe[idx]);
    cP[idx] = f2bf(hs);
    hs = fmaf(p, hs, he);
  }
}

// ---------------------------------------------------------------------------
// Scan phase 3 (CH=32): B/C staged to LDS; udt/zsb prefetch depth 2; h_start
// read bf16; gated y bf16.
// ---------------------------------------------------------------------------
__global__ __launch_bounds__(512, 4)
void scan_phase3(const unsigned int* __restrict__ udt,
                 const float* __restrict__ Bb, const float* __restrict__ Cb,
                 const float* __restrict__ alog, const unsigned short* __restrict__ hst,
                 const float* __restrict__ dsk,
                 const unsigned short* __restrict__ zsb,
                 unsigned short* __restrict__ yb) {
  __shared__ float Bs[CH * 16];   // 2 KB
  __shared__ float Cs[CH * 16];   // 2 KB
  const int bc = blockIdx.x;
  const int b = bc >> 7, c = bc & (NC - 1);
  const int t = threadIdx.x;
  const int l = t & 63, w = t >> 6;
  const int d = (w << 5) + (l & 31);
  const int sh = l >> 5;
  const int soff = sh << 3;
  const int base = b * L_ + c * CH;
  if (t < CH * 4)            ((float4*)Bs)[t]            = *(const float4*)&Bb[base * 16 + (t << 2)];
  else if (t < CH * 8)       ((float4*)Cs)[t - CH * 4]   = *(const float4*)&Cb[base * 16 + ((t - CH * 4) << 2)];
  float a[8];
  bool okl = true;
#pragma unroll
  for (int j = 0; j < 8; ++j) {
    a[j] = -__expf(alog[d * 16 + soff + j]);
    float tgt = (float)(soff + j + 1);
    okl = okl && (fabsf(a[j] + tgt) <= 1e-3f * tgt);
  }
  const bool fast = (bool)__all((int)okl);
  const float dskv = dsk[d];
  f32x2 h2[4];
#pragma unroll
  for (int j = 0; j < 8; ++j)
    h2[j >> 1][j & 1] = bf2f((unsigned int)hst[(bc * 16 + soff + j) * 256 + d]);
  unsigned int wv0 = udt[base * 256 + d];
  unsigned int wv1 = udt[(base + 1) * 256 + d];
  unsigned short zv0 = zsb[base * 256 + d];
  unsigned short zv1 = zsb[(base + 1) * 256 + d];
  __syncthreads();
#pragma unroll 4
  for (int ll = 0; ll < CH; ++ll) {
    const int m = base + ll;
    const int m2 = base + ((ll + 2 < CH) ? ll + 2 : CH - 1);
    unsigned int wv2 = udt[m2 * 256 + d];
    unsigned short zv2 = zsb[m2 * 256 + d];
    float4 b0 = *(const float4*)&Bs[ll * 16 + soff];
    float4 b1 = *(const float4*)&Bs[ll * 16 + soff + 4];
    float4 c0 = *(const float4*)&Cs[ll * 16 + soff];
    float4 c1 = *(const float4*)&Cs[ll * 16 + soff + 4];
    float uv  = bf2f(wv0 & 0xFFFFu);
    float dtv = bf2f(wv0 >> 16);
    f32x2 B2[4] = {{b0.x,b0.y},{b0.z,b0.w},{b1.x,b1.y},{b1.z,b1.w}};
    f32x2 C2[4] = {{c0.x,c0.y},{c0.z,c0.w},{c1.x,c1.y},{c1.z,c1.w}};
    float du = dtv * uv;
    f32x2 y2 = {0.f, 0.f};
    if (fast) {
      float e1 = __expf(-dtv);
      float e2 = e1 * e1, e4 = e2 * e2, e8 = e4 * e4;
      float st = sh ? e8 * e1 : e1;
      f32x2 dA = {st, st * e1};
      f32x2 e22 = {e2, e2};
      f32x2 du2 = {du, du};
#pragma unroll
      for (int j = 0; j < 4; ++j) {
        h2[j] = dA * h2[j] + du2 * B2[j];
        y2 = y2 + h2[j] * C2[j];
        dA = dA * e22;
      }
    } else {
#pragma unroll
      for (int j = 0; j < 8; ++j) {
        float dA = __expf(dtv * a[j]);
        float hh = fmaf(dA, h2[j >> 1][j & 1], du * B2[j >> 1][j & 1]);
        h2[j >> 1][j & 1] = hh;
        y2[j & 1] = fmaf(hh, C2[j >> 1][j & 1], y2[j & 1]);
      }
    }
    float y = y2.x + y2.y;
    y += __shfl_xor(y, 32);
    if (sh == 0) {
      float zs = bf2f((unsigned int)zv0);
      yb[m * 256 + d] = f2bf(fmaf(uv, dskv, y) * zs);
    }
    wv0 = wv1; wv1 = wv2; zv0 = zv1; zv1 = zv2;
  }
}

// ---------------------------------------------------------------------------
// LayerNorm(128) + fc(128x128) + ReLU via MFMA. Hin bf16.
// ---------------------------------------------------------------------------
__global__ __launch_bounds__(256)
void ln_fc_mfma(const unsigned short* __restrict__ Hin, const float* __restrict__ gamma,
                const float* __restrict__ beta, const float* __restrict__ fcw,
                float* __restrict__ out) {
  __shared__ unsigned short hnb[64 * 136];
  __shared__ unsigned short wb[128 * 136];
  const int t = threadIdx.x;
  const int p0 = blockIdx.x << 6;
  {
    const int r = t >> 2, qd = t & 3;
    const unsigned short* hp = &Hin[(p0 + r) * 128 + (qd << 5)];
    float v[32];
#pragma unroll
    for (int j = 0; j < 4; ++j) {
      uint4 hv = *(const uint4*)&hp[j << 3];   // 8 bf16
      unsigned int hw[4] = {hv.x, hv.y, hv.z, hv.w};
#pragma unroll
      for (int k2 = 0; k2 < 4; ++k2) {
        v[(j << 3) + 2*k2]     = bf2f(hw[k2] & 0xFFFFu);
        v[(j << 3) + 2*k2 + 1] = bf2f(hw[k2] >> 16);
      }
    }
    float s1 = 0.f, s2 = 0.f;
#pragma unroll
    for (int j = 0; j < 32; ++j) { s1 += v[j]; s2 = fmaf(v[j], v[j], s2); }
    s1 += __shfl_xor(s1, 1); s2 += __shfl_xor(s2, 1);
    s1 += __shfl_xor(s1, 2); s2 += __shfl_xor(s2, 2);
    float mu = s1 * (1.f / DM);
    float var = s2 * (1.f / DM) - mu * mu;
    float rs = rsqrtf(var + 1e-5f);
    const float* gp = &gamma[qd << 5];
    const float* bp = &beta[qd << 5];
#pragma unroll
    for (int j = 0; j < 16; ++j) {
      float h0 = fmaf((v[2*j]   - mu) * rs, gp[2*j],   bp[2*j]);
      float h1 = fmaf((v[2*j+1] - mu) * rs, gp[2*j+1], bp[2*j+1]);
      *(unsigned int*)&hnb[r * 136 + (qd << 5) + 2*j] = f2bf2(h0, h1);
    }
  }
  for (int i = t; i < 128 * 32; i += 256) {
    int row = i >> 5, c4 = i & 31;
    float4 wv = *(const float4*)&fcw[row * 128 + (c4 << 2)];
    uint2 wp = {f2bf2(wv.x, wv.y), f2bf2(wv.z, wv.w)};
    *(uint2*)&wb[row * 136 + (c4 << 2)] = wp;
  }
  __syncthreads();
  const int w = t >> 6, l = t & 63, q = l >> 4, col = l & 15;
  ffrag acc[8] = {{0.f,0.f,0.f,0.f},{0.f,0.f,0.f,0.f},{0.f,0.f,0.f,0.f},{0.f,0.f,0.f,0.f},
                  {0.f,0.f,0.f,0.f},{0.f,0.f,0.f,0.f},{0.f,0.f,0.f,0.f},{0.f,0.f,0.f,0.f}};
#pragma unroll
  for (int s = 0; s < 4; ++s) {
    int k0 = s * 32 + q * 8;
    bfrag af = *(const bfrag*)&hnb[((w << 4) + col) * 136 + k0];
#pragma unroll
    for (int nt = 0; nt < 8; ++nt) {
      bfrag bf_ = *(const bfrag*)&wb[((nt << 4) + col) * 136 + k0];
      acc[nt] = __builtin_amdgcn_mfma_f32_16x16x32_bf16(af, bf_, acc[nt], 0, 0, 0);
    }
  }
#pragma unroll
  for (int nt = 0; nt < 8; ++nt)
#pragma unroll
    for (int i = 0; i < 4; ++i) {
      int ml = (w << 4) + (q << 2) + i;
      out[(p0 + ml) * 128 + (nt << 4) + col] = fmaxf(acc[nt][i], 0.f);
    }
}

extern "C" void kernel_launch(void* const* d_in, const int* in_sizes, int n_in,
                              void* d_out, int out_size, void* d_ws, size_t ws_size,
                              hipStream_t stream) {
  (void)in_sizes; (void)n_in; (void)out_size; (void)ws_size;
  const float* s    = (const float*)d_in[0];
  const float* w_in = (const float*)d_in[1];
  const float* cw   = (const float*)d_in[2];
  const float* cb   = (const float*)d_in[3];
  const float* xw   = (const float*)d_in[4];
  const float* dtw  = (const float*)d_in[5];
  const float* dtpb = (const float*)d_in[6];
  const float* alog = (const float*)d_in[7];
  const float* dsk  = (const float*)d_in[8];
  const float* ow   = (const float*)d_in[9];
  const float* gam  = (const float*)d_in[10];
  const float* bet  = (const float*)d_in[11];
  const float* fcw  = (const float*)d_in[12];
  float* out = (float*)d_out;
  float* ws  = (float*)d_ws;

  // float-unit offsets; all regions disjoint (audited):
  // cP/cHe: B_*NC*4096 = 4194304 bf16 elements = 8.4 MB each (same bytes as
  // the NC=64 f32 layout).
  unsigned short* xb   = (unsigned short*)ws;                 // [0, 4194304)
  unsigned short* zsb  = (unsigned short*)(ws + 4194304);     // [4194304, 8388608)
  unsigned int*   udt  = (unsigned int*)(ws + 8388608);       // [8388608, 16777216)
  float*          Bb   = ws + 16777216;                       // [16777216, 17301504)
  float*          Cb   = ws + 17301504;                       // [17301504, 17825792)
  unsigned short* cP   = (unsigned short*)(ws + 17825792);    // [17825792, 19922944)
  unsigned short* cHe  = (unsigned short*)(ws + 19922944);    // [19922944, 22020096)
  unsigned short* yb   = (unsigned short*)(ws + 22020096);    // [22020096, 26214400)
  unsigned short* hmid = (unsigned short*)(ws + 26214400);    // [26214400, 28311552)

  // 1. in_proj (bf16 MFMA, half-split + W pipeline): x -> xb, z -> silu -> zsb
  gemm_bf16_in<<<dim3(2, 512), 256, 0, stream>>>(s, w_in, xb, zsb);
  // 2. fused conv/silu + x_proj (MFMA) + dt_proj (fast softplus); emits udt
  xproj_dtproj<<<512, 512, 0, stream>>>(xb, xw, dtw, dtpb, cw, cb, Bb, Cb, udt);
  // 3-5. chunked selective scan (CH=32, full occupancy, bf16 intermediates)
  scan_phase1<<<B_ * NC, 512, 0, stream>>>(udt, Bb, alog, cP, cHe);
  scan_combine<<<512, 512, 0, stream>>>(cP, cHe);
  scan_phase3<<<B_ * NC, 512, 0, stream>>>(udt, Bb, Cb, alog, cP, dsk, zsb, yb);
  // 6. out_proj (bf16 MFMA) from gated yb -> hmid bf16
  gemm_bf16_out<<<dim3(2, 512), 256, 0, stream>>>(yb, ow, hmid);
  // 7. LayerNorm + fc + ReLU (bf16 MFMA), bf16 input
  ln_fc_mfma<<<512, 256, 0, stream>>>(hmid, gam, bet, fcw, out);
}

// Round 19
// 196.635 us; speedup vs baseline: 1.0574x; 1.0574x over previous
//
#include <hip/hip_runtime.h>
#include <math.h>

#define B_ 8
#define L_ 4096
#define DM 128
#define DI 256
#define DSN 16
#define RK 8
#define M_ (B_*L_)      // 32768 positions
#define NC 128          // number of scan chunks
#define CH 32           // chunk length (NC*CH == L_)

typedef __attribute__((ext_vector_type(8))) short bfrag;   // 8 bf16 (4 VGPRs)
typedef __attribute__((ext_vector_type(4))) float ffrag;   // 4 fp32 acc
typedef __attribute__((ext_vector_type(2))) float f32x2;   // packed-math pair

// fast silu: v_exp + v_rcp (hardware approx, ~22-bit — far above bf16 needs)
__device__ __forceinline__ float silu_f(float x) {
  return x * __builtin_amdgcn_rcpf(1.f + __expf(-x));
}
// fast softplus: v_exp + v_log instead of libm log1pf
__device__ __forceinline__ float softplus_f(float x) {
  return (x > 20.f) ? x : __logf(1.f + __expf(x));
}

__device__ __forceinline__ unsigned short f2bf(float f) {
  unsigned int u = __builtin_bit_cast(unsigned int, f);
  unsigned int r = (u + 0x7FFFu + ((u >> 16) & 1u)) >> 16;   // RNE
  return (unsigned short)r;
}
__device__ __forceinline__ unsigned int f2bf2(float lo, float hi) {
  return (unsigned int)f2bf(lo) | ((unsigned int)f2bf(hi) << 16);
}
__device__ __forceinline__ float bf2f(unsigned int us) {
  return __builtin_bit_cast(float, us << 16);
}

// ---------------------------------------------------------------------------
// in_proj bf16 MFMA GEMM, half-split + reg-prefetch W pipeline + LDS-staged
// vectorized output. Grid (2, 512): blockIdx.x = output half (0: xb, 1: zsb
// with fused silu).
// ---------------------------------------------------------------------------
__global__ __launch_bounds__(256)
void gemm_bf16_in(const float* __restrict__ A, const float* __restrict__ W,
                  unsigned short* __restrict__ xb, unsigned short* __restrict__ zsb) {
  __shared__ unsigned short As[64 * 136];   // 17.4 KB
  __shared__ unsigned short Ws[64 * 136];   // 17.4 KB
  __shared__ unsigned short Os[64 * 72];    // 9.2 KB
  const int t = threadIdx.x;
  const int m0 = blockIdx.y << 6;
  const int half = blockIdx.x;              // 0 -> xb, 1 -> zsb (silu)
  unsigned short* __restrict__ outp = half ? zsb : xb;
  const float* __restrict__ Wbase = W + (half << 8) * 128;
  for (int i = t; i < 64 * 32; i += 256) {
    int row = i >> 5, c4 = i & 31;
    float4 av = *(const float4*)&A[(m0 + row) * 128 + (c4 << 2)];
    uint2 ap = {f2bf2(av.x, av.y), f2bf2(av.z, av.w)};
    *(uint2*)&As[row * 136 + (c4 << 2)] = ap;
  }
  float4 wr[8];
#pragma unroll
  for (int k = 0; k < 8; ++k) {
    int i = t + (k << 8);
    int row = i >> 5, c4 = i & 31;
    wr[k] = *(const float4*)&Wbase[row * 128 + (c4 << 2)];
  }
#pragma unroll
  for (int k = 0; k < 8; ++k) {
    int i = t + (k << 8);
    int row = i >> 5, c4 = i & 31;
    uint2 wp = {f2bf2(wr[k].x, wr[k].y), f2bf2(wr[k].z, wr[k].w)};
    *(uint2*)&Ws[row * 136 + (c4 << 2)] = wp;
  }
  __syncthreads();
  const int w = t >> 6, l = t & 63, q = l >> 4, col = l & 15;
  for (int jt = 0; jt < 4; ++jt) {
    if (jt < 3) {
#pragma unroll
      for (int k = 0; k < 8; ++k) {
        int i = t + (k << 8);
        int row = i >> 5, c4 = i & 31;
        wr[k] = *(const float4*)&Wbase[(((jt + 1) << 6) + row) * 128 + (c4 << 2)];
      }
    }
    ffrag acc[4] = {{0.f,0.f,0.f,0.f},{0.f,0.f,0.f,0.f},{0.f,0.f,0.f,0.f},{0.f,0.f,0.f,0.f}};
#pragma unroll
    for (int s = 0; s < 4; ++s) {
      int k0 = s * 32 + q * 8;
      bfrag af = *(const bfrag*)&As[((w << 4) + col) * 136 + k0];
#pragma unroll
      for (int nt = 0; nt < 4; ++nt) {
        bfrag bf_ = *(const bfrag*)&Ws[((nt << 4) + col) * 136 + k0];
        acc[nt] = __builtin_amdgcn_mfma_f32_16x16x32_bf16(af, bf_, acc[nt], 0, 0, 0);
      }
    }
    __syncthreads();
#pragma unroll
    for (int nt = 0; nt < 4; ++nt)
#pragma unroll
      for (int i = 0; i < 4; ++i) {
        int ml = (w << 4) + (q << 2) + i;
        float v = acc[nt][i];
        if (half) v = silu_f(v);
        Os[ml * 72 + (nt << 4) + col] = f2bf(v);
      }
    if (jt < 3) {
#pragma unroll
      for (int k = 0; k < 8; ++k) {
        int i = t + (k << 8);
        int row = i >> 5, c4 = i & 31;
        uint2 wp = {f2bf2(wr[k].x, wr[k].y), f2bf2(wr[k].z, wr[k].w)};
        *(uint2*)&Ws[row * 136 + (c4 << 2)] = wp;
      }
    }
    __syncthreads();
    {
      int r = t >> 2, c8 = (t & 3) << 3;
      int m = m0 + r;
      *(uint4*)&outp[m * 256 + (jt << 6) + c8]      = *(const uint4*)&Os[r * 72 + c8];
      *(uint4*)&outp[m * 256 + (jt << 6) + 32 + c8] = *(const uint4*)&Os[r * 72 + 32 + c8];
    }
  }
}

// ---------------------------------------------------------------------------
// FUSED out_proj + LayerNorm + fc + ReLU. One block per 64-position m-tile.
// Pass 1: out_proj (2 n-tile passes, single Ws buffer). LN entirely in
// registers (row spans the 16 lanes of a quad-group; 4 shfl_xor levels).
// hnb overlays As; fcw overlays Ws. hmid never materializes (f32 in regs).
// ---------------------------------------------------------------------------
__global__ __launch_bounds__(256)
void out_ln_fc(const unsigned short* __restrict__ Yb, const float* __restrict__ W,
               const float* __restrict__ gamma, const float* __restrict__ beta,
               const float* __restrict__ fcw, float* __restrict__ out) {
  __shared__ unsigned short smA[64 * 264];    // As (yb); later hnb (stride 136)
  __shared__ unsigned short smB[128 * 136];   // Ws (stride 264, 64 rows); later fcw
  const int t = threadIdx.x;
  const int m0 = blockIdx.x << 6;
  // stage A (yb)
  for (int i = t; i < 64 * 32; i += 256) {
    int row = i >> 5, c8 = i & 31;
    uint4 av = *(const uint4*)&Yb[(m0 + row) * 256 + (c8 << 3)];
    *(uint4*)&smA[row * 264 + (c8 << 3)] = av;
  }
  const int w = t >> 6, l = t & 63, q = l >> 4, col = l & 15;
  ffrag acc[2][4];
  for (int nt2 = 0; nt2 < 2; ++nt2) {
    __syncthreads();           // smB free (iter0: covers As staging too)
    for (int i = t; i < 64 * 64; i += 256) {
      int row = i >> 6, c4 = i & 63;
      float4 wv = *(const float4*)&W[((nt2 << 6) + row) * 256 + (c4 << 2)];
      uint2 wp = {f2bf2(wv.x, wv.y), f2bf2(wv.z, wv.w)};
      *(uint2*)&smB[row * 264 + (c4 << 2)] = wp;
    }
    __syncthreads();
#pragma unroll
    for (int nt = 0; nt < 4; ++nt) acc[nt2][nt] = (ffrag){0.f, 0.f, 0.f, 0.f};
#pragma unroll
    for (int s = 0; s < 8; ++s) {
      int k0 = s * 32 + q * 8;
      bfrag af = *(const bfrag*)&smA[((w << 4) + col) * 264 + k0];
#pragma unroll
      for (int nt = 0; nt < 4; ++nt) {
        bfrag bf_ = *(const bfrag*)&smB[((nt << 4) + col) * 264 + k0];
        acc[nt2][nt] = __builtin_amdgcn_mfma_f32_16x16x32_bf16(af, bf_, acc[nt2][nt], 0, 0, 0);
      }
    }
  }
  // LN stats per row (i = 0..3); row's 128 cols live across the 16 lanes of
  // this quad-group (l = q*16 + col) with 8 values per lane.
  float mu[4], rs[4];
#pragma unroll
  for (int i = 0; i < 4; ++i) {
    float s1 = 0.f, s2 = 0.f;
#pragma unroll
    for (int nt2 = 0; nt2 < 2; ++nt2)
#pragma unroll
      for (int nt = 0; nt < 4; ++nt) {
        float v = acc[nt2][nt][i];
        s1 += v; s2 = fmaf(v, v, s2);
      }
    s1 += __shfl_xor(s1, 1); s2 += __shfl_xor(s2, 1);
    s1 += __shfl_xor(s1, 2); s2 += __shfl_xor(s2, 2);
    s1 += __shfl_xor(s1, 4); s2 += __shfl_xor(s2, 4);
    s1 += __shfl_xor(s1, 8); s2 += __shfl_xor(s2, 8);
    mu[i] = s1 * (1.f / DM);
    float var = s2 * (1.f / DM) - mu[i] * mu[i];
    rs[i] = rsqrtf(var + 1e-5f);
  }
  __syncthreads();   // all MFMA LDS reads done before overlaying smA/smB
  // normalized values -> hnb (overlay smA, stride 136)
#pragma unroll
  for (int nt2 = 0; nt2 < 2; ++nt2)
#pragma unroll
    for (int nt = 0; nt < 4; ++nt) {
      int n = (nt2 << 6) + (nt << 4) + col;
      float g = gamma[n], be = beta[n];
#pragma unroll
      for (int i = 0; i < 4; ++i) {
        int r = (w << 4) + (q << 2) + i;
        smA[r * 136 + n] = f2bf(fmaf((acc[nt2][nt][i] - mu[i]) * rs[i], g, be));
      }
    }
  // stage fcw (overlay smB, stride 136, 128 rows)
  for (int i = t; i < 128 * 32; i += 256) {
    int row = i >> 5, c4 = i & 31;
    float4 wv = *(const float4*)&fcw[row * 128 + (c4 << 2)];
    uint2 wp = {f2bf2(wv.x, wv.y), f2bf2(wv.z, wv.w)};
    *(uint2*)&smB[row * 136 + (c4 << 2)] = wp;
  }
  __syncthreads();
  // fc MFMA: wave w -> m-tile w, 8 n-tiles, K=128 (4 steps), + ReLU store
  ffrag a2[8] = {{0.f,0.f,0.f,0.f},{0.f,0.f,0.f,0.f},{0.f,0.f,0.f,0.f},{0.f,0.f,0.f,0.f},
                 {0.f,0.f,0.f,0.f},{0.f,0.f,0.f,0.f},{0.f,0.f,0.f,0.f},{0.f,0.f,0.f,0.f}};
#pragma unroll
  for (int s = 0; s < 4; ++s) {
    int k0 = s * 32 + q * 8;
    bfrag af = *(const bfrag*)&smA[((w << 4) + col) * 136 + k0];
#pragma unroll
    for (int nt = 0; nt < 8; ++nt) {
      bfrag bf_ = *(const bfrag*)&smB[((nt << 4) + col) * 136 + k0];
      a2[nt] = __builtin_amdgcn_mfma_f32_16x16x32_bf16(af, bf_, a2[nt], 0, 0, 0);
    }
  }
#pragma unroll
  for (int nt = 0; nt < 8; ++nt)
#pragma unroll
    for (int i = 0; i < 4; ++i) {
      int ml = (w << 4) + (q << 2) + i;
      out[(m0 + ml) * 128 + (nt << 4) + col] = fmaxf(a2[nt][i], 0.f);
    }
}

// ---------------------------------------------------------------------------
// Fused conv(4)+SiLU -> bf16 LDS -> MFMA x_proj -> dt_proj + softplus.
// ---------------------------------------------------------------------------
__global__ __launch_bounds__(512)
void xproj_dtproj(const unsigned short* __restrict__ xb, const float* __restrict__ xw,
                  const float* __restrict__ dtw, const float* __restrict__ dtpb,
                  const float* __restrict__ cw, const float* __restrict__ cb,
                  float* __restrict__ Bb, float* __restrict__ Cb,
                  unsigned int* __restrict__ udt) {
  __shared__ unsigned short ua[64 * 264];   // u bf16
  __shared__ unsigned short wb[48 * 264];   // xw bf16; rows 40..47 zeroed
  __shared__ float dtr_s[64 * 12];
  const int t = threadIdx.x;
  const int p0 = blockIdx.x << 6;
  {
    const int k = t & 255, half = t >> 8;
    const int pstart = half << 5;
    const int base = p0 + pstart;
    const int lb = base & (L_ - 1);
    const float w0 = cw[k*4], w1 = cw[k*4+1], w2 = cw[k*4+2], w3 = cw[k*4+3];
    const float bias = cb[k];
    float x0 = (lb >= 3) ? bf2f((unsigned int)xb[(base - 3) * 256 + k]) : 0.f;
    float x1 = (lb >= 2) ? bf2f((unsigned int)xb[(base - 2) * 256 + k]) : 0.f;
    float x2 = (lb >= 1) ? bf2f((unsigned int)xb[(base - 1) * 256 + k]) : 0.f;
#pragma unroll 8
    for (int it = 0; it < 32; ++it) {
      float x3 = bf2f((unsigned int)xb[(base + it) * 256 + k]);
      float u = silu_f(fmaf(w0, x0, fmaf(w1, x1, fmaf(w2, x2, fmaf(w3, x3, bias)))));
      ua[(pstart + it) * 264 + k] = f2bf(u);
      x0 = x1; x1 = x2; x2 = x3;
    }
  }
  for (int i = t; i < 40 * 256; i += 512) {
    int n = i >> 8, k = i & 255;
    wb[n * 264 + k] = f2bf(xw[i]);
  }
  for (int i = t; i < 8 * 264; i += 512) wb[40 * 264 + i] = 0;
  __syncthreads();
  const int w = t >> 6, l = t & 63, q = l >> 4, col = l & 15;
  for (int tile = w; tile < 12; tile += 8) {
    const int mt = tile & 3, nt = tile >> 2;
    ffrag acc = {0.f, 0.f, 0.f, 0.f};
#pragma unroll
    for (int s = 0; s < 8; ++s) {
      int k0 = s * 32 + q * 8;
      bfrag af = *(const bfrag*)&ua[((mt << 4) + col) * 264 + k0];
      bfrag bf_ = *(const bfrag*)&wb[((nt << 4) + col) * 264 + k0];
      acc = __builtin_amdgcn_mfma_f32_16x16x32_bf16(af, bf_, acc, 0, 0, 0);
    }
#pragma unroll
    for (int i = 0; i < 4; ++i) {
      int ml = (mt << 4) + (q << 2) + i;
      int m = p0 + ml;
      if (nt == 0) {
        if (col < 8) dtr_s[ml * 12 + col] = acc[i];
        else         Bb[m * 16 + (col - 8)] = acc[i];
      } else if (nt == 1) {
        if (col < 8) Bb[m * 16 + 8 + col] = acc[i];
        else         Cb[m * 16 + (col - 8)] = acc[i];
      } else {
        if (col < 8) Cb[m * 16 + 8 + col] = acc[i];
      }
    }
  }
  __syncthreads();
  {
    const int d = t & 255, half = t >> 8;
    const int pstart = half << 5;
    float w8[8];
    *(float4*)&w8[0] = *(const float4*)&dtw[d * 8];
    *(float4*)&w8[4] = *(const float4*)&dtw[d * 8 + 4];
    const float bias = dtpb[d];
#pragma unroll 4
    for (int pp = pstart; pp < pstart + 32; ++pp) {
      float r0[8];
      *(float4*)&r0[0] = *(const float4*)&dtr_s[pp * 12];
      *(float4*)&r0[4] = *(const float4*)&dtr_s[pp * 12 + 4];
      float a2 = bias;
#pragma unroll
      for (int r2 = 0; r2 < 8; ++r2) a2 = fmaf(r0[r2], w8[r2], a2);
      float sp = softplus_f(a2);
      udt[(p0 + pp) * 256 + d] =
          (unsigned int)ua[pp * 264 + d] | ((unsigned int)f2bf(sp) << 16);
    }
  }
}

// ---------------------------------------------------------------------------
// Scan phase 1 (CH=32): B staged to LDS; udt prefetch depth 2; cP/cHe bf16.
// ---------------------------------------------------------------------------
__global__ __launch_bounds__(512, 4)
void scan_phase1(const unsigned int* __restrict__ udt,
                 const float* __restrict__ Bb, const float* __restrict__ alog,
                 unsigned short* __restrict__ cP, unsigned short* __restrict__ cHe) {
  __shared__ float Bs[CH * 16];   // 2 KB
  const int bc = blockIdx.x;
  const int b = bc >> 7, c = bc & (NC - 1);
  const int t = threadIdx.x;
  const int l = t & 63, w = t >> 6;
  const int d = (w << 5) + (l & 31);
  const int sh = l >> 5;
  const int soff = sh << 3;
  const int base = b * L_ + c * CH;
  if (t < CH * 4) ((float4*)Bs)[t] = *(const float4*)&Bb[base * 16 + (t << 2)];
  float a[8];
  bool okl = true;
#pragma unroll
  for (int j = 0; j < 8; ++j) {
    a[j] = -__expf(alog[d * 16 + soff + j]);
    float tgt = (float)(soff + j + 1);
    okl = okl && (fabsf(a[j] + tgt) <= 1e-3f * tgt);
  }
  const bool fast = (bool)__all((int)okl);
  f32x2 h2[4] = {{0.f,0.f},{0.f,0.f},{0.f,0.f},{0.f,0.f}};
  float sdt = 0.f;
  unsigned int wv0 = udt[base * 256 + d];
  unsigned int wv1 = udt[(base + 1) * 256 + d];
  __syncthreads();
#pragma unroll 4
  for (int ll = 0; ll < CH; ++ll) {
    const int m2 = base + ((ll + 2 < CH) ? ll + 2 : CH - 1);
    unsigned int wv2 = udt[m2 * 256 + d];
    float4 b0 = *(const float4*)&Bs[ll * 16 + soff];
    float4 b1 = *(const float4*)&Bs[ll * 16 + soff + 4];
    float uv  = bf2f(wv0 & 0xFFFFu);
    float dtv = bf2f(wv0 >> 16);
    f32x2 B2[4] = {{b0.x,b0.y},{b0.z,b0.w},{b1.x,b1.y},{b1.z,b1.w}};
    float du = dtv * uv;
    sdt += dtv;
    if (fast) {
      float e1 = __expf(-dtv);
      float e2 = e1 * e1, e4 = e2 * e2, e8 = e4 * e4;
      float st = sh ? e8 * e1 : e1;
      f32x2 dA = {st, st * e1};
      f32x2 e22 = {e2, e2};
      f32x2 du2 = {du, du};
#pragma unroll
      for (int j = 0; j < 4; ++j) {
        h2[j] = dA * h2[j] + du2 * B2[j];
        dA = dA * e22;
      }
    } else {
#pragma unroll
      for (int j = 0; j < 8; ++j) {
        float dA = __expf(dtv * a[j]);
        h2[j >> 1][j & 1] = fmaf(dA, h2[j >> 1][j & 1], du * B2[j >> 1][j & 1]);
      }
    }
    wv0 = wv1; wv1 = wv2;
  }
#pragma unroll
  for (int j = 0; j < 8; ++j) {
    int o = (bc * 16 + soff + j) * 256 + d;
    cP[o]  = f2bf(__expf(a[j] * sdt));
    cHe[o] = f2bf(h2[j >> 1][j & 1]);
  }
}

// ---------------------------------------------------------------------------
// Hierarchical combine (NC=128, bf16): 512 thr = 64 sd x 8 segments of 16.
// ---------------------------------------------------------------------------
__global__ __launch_bounds__(512)
void scan_combine(unsigned short* __restrict__ cP, const unsigned short* __restrict__ cHe) {
  __shared__ float segP[64 * 9], segH[64 * 9], segS[64 * 9];
  const int t = threadIdx.x;
  const int sdl = t & 63, seg = t >> 6;
  const int blk = blockIdx.x;
  const int b = blk >> 6, grp = blk & 63;
  const int sd = (grp << 6) + sdl;
  const int base = b * NC * 4096 + sd;
  float Pacc = 1.f, Hacc = 0.f;
#pragma unroll
  for (int i = 0; i < 16; ++i) {
    int idx = base + (seg * 16 + i) * 4096;
    float p = bf2f((unsigned int)cP[idx]);
    float he = bf2f((unsigned int)cHe[idx]);
    Hacc = fmaf(p, Hacc, he);
    Pacc *= p;
  }
  segP[sdl * 9 + seg] = Pacc;
  segH[sdl * 9 + seg] = Hacc;
  __syncthreads();
  if (t < 64) {
    float hs = 0.f;
#pragma unroll
    for (int s2 = 0; s2 < 8; ++s2) {
      segS[t * 9 + s2] = hs;
      hs = fmaf(segP[t * 9 + s2], hs, segH[t * 9 + s2]);
    }
  }
  __syncthreads();
  float hs = segS[sdl * 9 + seg];
#pragma unroll
  for (int i = 0; i < 16; ++i) {
    int idx = base + (seg * 16 + i) * 4096;
    float p = bf2f((unsigned int)cP[idx]);
    float he = bf2f((unsigned int)cHe[idx]);
    cP[idx] = f2bf(hs);
    hs = fmaf(p, hs, he);
  }
}

// ---------------------------------------------------------------------------
// Scan phase 3 (CH=32): B/C staged to LDS; udt/zsb prefetch depth 2; h_start
// read bf16; gated y bf16.
// ---------------------------------------------------------------------------
__global__ __launch_bounds__(512, 4)
void scan_phase3(const unsigned int* __restrict__ udt,
                 const float* __restrict__ Bb, const float* __restrict__ Cb,
                 const float* __restrict__ alog, const unsigned short* __restrict__ hst,
                 const float* __restrict__ dsk,
                 const unsigned short* __restrict__ zsb,
                 unsigned short* __restrict__ yb) {
  __shared__ float Bs[CH * 16];   // 2 KB
  __shared__ float Cs[CH * 16];   // 2 KB
  const int bc = blockIdx.x;
  const int b = bc >> 7, c = bc & (NC - 1);
  const int t = threadIdx.x;
  const int l = t & 63, w = t >> 6;
  const int d = (w << 5) + (l & 31);
  const int sh = l >> 5;
  const int soff = sh << 3;
  const int base = b * L_ + c * CH;
  if (t < CH * 4)            ((float4*)Bs)[t]            = *(const float4*)&Bb[base * 16 + (t << 2)];
  else if (t < CH * 8)       ((float4*)Cs)[t - CH * 4]   = *(const float4*)&Cb[base * 16 + ((t - CH * 4) << 2)];
  float a[8];
  bool okl = true;
#pragma unroll
  for (int j = 0; j < 8; ++j) {
    a[j] = -__expf(alog[d * 16 + soff + j]);
    float tgt = (float)(soff + j + 1);
    okl = okl && (fabsf(a[j] + tgt) <= 1e-3f * tgt);
  }
  const bool fast = (bool)__all((int)okl);
  const float dskv = dsk[d];
  f32x2 h2[4];
#pragma unroll
  for (int j = 0; j < 8; ++j)
    h2[j >> 1][j & 1] = bf2f((unsigned int)hst[(bc * 16 + soff + j) * 256 + d]);
  unsigned int wv0 = udt[base * 256 + d];
  unsigned int wv1 = udt[(base + 1) * 256 + d];
  unsigned short zv0 = zsb[base * 256 + d];
  unsigned short zv1 = zsb[(base + 1) * 256 + d];
  __syncthreads();
#pragma unroll 4
  for (int ll = 0; ll < CH; ++ll) {
    const int m = base + ll;
    const int m2 = base + ((ll + 2 < CH) ? ll + 2 : CH - 1);
    unsigned int wv2 = udt[m2 * 256 + d];
    unsigned short zv2 = zsb[m2 * 256 + d];
    float4 b0 = *(const float4*)&Bs[ll * 16 + soff];
    float4 b1 = *(const float4*)&Bs[ll * 16 + soff + 4];
    float4 c0 = *(const float4*)&Cs[ll * 16 + soff];
    float4 c1 = *(const float4*)&Cs[ll * 16 + soff + 4];
    float uv  = bf2f(wv0 & 0xFFFFu);
    float dtv = bf2f(wv0 >> 16);
    f32x2 B2[4] = {{b0.x,b0.y},{b0.z,b0.w},{b1.x,b1.y},{b1.z,b1.w}};
    f32x2 C2[4] = {{c0.x,c0.y},{c0.z,c0.w},{c1.x,c1.y},{c1.z,c1.w}};
    float du = dtv * uv;
    f32x2 y2 = {0.f, 0.f};
    if (fast) {
      float e1 = __expf(-dtv);
      float e2 = e1 * e1, e4 = e2 * e2, e8 = e4 * e4;
      float st = sh ? e8 * e1 : e1;
      f32x2 dA = {st, st * e1};
      f32x2 e22 = {e2, e2};
      f32x2 du2 = {du, du};
#pragma unroll
      for (int j = 0; j < 4; ++j) {
        h2[j] = dA * h2[j] + du2 * B2[j];
        y2 = y2 + h2[j] * C2[j];
        dA = dA * e22;
      }
    } else {
#pragma unroll
      for (int j = 0; j < 8; ++j) {
        float dA = __expf(dtv * a[j]);
        float hh = fmaf(dA, h2[j >> 1][j & 1], du * B2[j >> 1][j & 1]);
        h2[j >> 1][j & 1] = hh;
        y2[j & 1] = fmaf(hh, C2[j >> 1][j & 1], y2[j & 1]);
      }
    }
    float y = y2.x + y2.y;
    y += __shfl_xor(y, 32);
    if (sh == 0) {
      float zs = bf2f((unsigned int)zv0);
      yb[m * 256 + d] = f2bf(fmaf(uv, dskv, y) * zs);
    }
    wv0 = wv1; wv1 = wv2; zv0 = zv1; zv1 = zv2;
  }
}

extern "C" void kernel_launch(void* const* d_in, const int* in_sizes, int n_in,
                              void* d_out, int out_size, void* d_ws, size_t ws_size,
                              hipStream_t stream) {
  (void)in_sizes; (void)n_in; (void)out_size; (void)ws_size;
  const float* s    = (const float*)d_in[0];
  const float* w_in = (const float*)d_in[1];
  const float* cw   = (const float*)d_in[2];
  const float* cb   = (const float*)d_in[3];
  const float* xw   = (const float*)d_in[4];
  const float* dtw  = (const float*)d_in[5];
  const float* dtpb = (const float*)d_in[6];
  const float* alog = (const float*)d_in[7];
  const float* dsk  = (const float*)d_in[8];
  const float* ow   = (const float*)d_in[9];
  const float* gam  = (const float*)d_in[10];
  const float* bet  = (const float*)d_in[11];
  const float* fcw  = (const float*)d_in[12];
  float* out = (float*)d_out;
  float* ws  = (float*)d_ws;

  // float-unit offsets; all regions disjoint (audited):
  unsigned short* xb   = (unsigned short*)ws;                 // [0, 4194304)
  unsigned short* zsb  = (unsigned short*)(ws + 4194304);     // [4194304, 8388608)
  unsigned int*   udt  = (unsigned int*)(ws + 8388608);       // [8388608, 16777216)
  float*          Bb   = ws + 16777216;                       // [16777216, 17301504)
  float*          Cb   = ws + 17301504;                       // [17301504, 17825792)
  unsigned short* cP   = (unsigned short*)(ws + 17825792);    // [17825792, 19922944)
  unsigned short* cHe  = (unsigned short*)(ws + 19922944);    // [19922944, 22020096)
  unsigned short* yb   = (unsigned short*)(ws + 22020096);    // [22020096, 26214400)

  // 1. in_proj (bf16 MFMA, half-split + W pipeline): x -> xb, z -> silu -> zsb
  gemm_bf16_in<<<dim3(2, 512), 256, 0, stream>>>(s, w_in, xb, zsb);
  // 2. fused conv/silu + x_proj (MFMA) + dt_proj (fast softplus); emits udt
  xproj_dtproj<<<512, 512, 0, stream>>>(xb, xw, dtw, dtpb, cw, cb, Bb, Cb, udt);
  // 3-5. chunked selective scan (CH=32, bf16 intermediates)
  scan_phase1<<<B_ * NC, 512, 0, stream>>>(udt, Bb, alog, cP, cHe);
  scan_combine<<<512, 512, 0, stream>>>(cP, cHe);
  scan_phase3<<<B_ * NC, 512, 0, stream>>>(udt, Bb, Cb, alog, cP, dsk, zsb, yb);
  // 6. FUSED out_proj + LayerNorm + fc + ReLU (hmid never materializes)
  out_ln_fc<<<512, 256, 0, stream>>>(yb, ow, gam, bet, fcw, out);
}